// Round 7
// baseline (485.937 us; speedup 1.0000x reference)
//
#include <hip/hip_runtime.h>
#include <hip/hip_bf16.h>
#include <hip/hip_cooperative_groups.h>

namespace cg = cooperative_groups;

#define N_SEQ 4096
#define DIM   128
#define NH    4
#define DH    32
#define BATCH 4

// scale = (1/sqrt(32)) * log2(e): softmax computed in exp2 domain
#define QSCALE 0.25503495870989204f

typedef __bf16 bf16x8 __attribute__((ext_vector_type(8)));
typedef __bf16 bf16x2 __attribute__((ext_vector_type(2)));
typedef __bf16 bf16x4 __attribute__((ext_vector_type(4)));
typedef float  f32x4  __attribute__((ext_vector_type(4)));

#define MFMA(a, b, c) __builtin_amdgcn_mfma_f32_16x16x32_bf16((a), (b), (c), 0, 0, 0)

static __device__ __forceinline__ bf16x8 cvt8(const float* __restrict__ p) {
    const float4* f4 = reinterpret_cast<const float4*>(p);
    float4 a = f4[0], b = f4[1];
    bf16x8 r;
    r[0] = (__bf16)a.x; r[1] = (__bf16)a.y; r[2] = (__bf16)a.z; r[3] = (__bf16)a.w;
    r[4] = (__bf16)b.x; r[5] = (__bf16)b.y; r[6] = (__bf16)b.z; r[7] = (__bf16)b.w;
    return r;
}

static __device__ __forceinline__ f32x4 exp4(f32x4 s) {
    f32x4 r;
    r[0] = __builtin_amdgcn_exp2f(s[0]);
    r[1] = __builtin_amdgcn_exp2f(s[1]);
    r[2] = __builtin_amdgcn_exp2f(s[2]);
    r[3] = __builtin_amdgcn_exp2f(s[3]);
    return r;
}

static __device__ __forceinline__ bf16x8 pack8(f32x4 a, f32x4 b) {
    bf16x8 o;
    o[0] = (__bf16)a[0]; o[1] = (__bf16)a[1];
    o[2] = (__bf16)a[2]; o[3] = (__bf16)a[3];
    o[4] = (__bf16)b[0]; o[5] = (__bf16)b[1];
    o[6] = (__bf16)b[2]; o[7] = (__bf16)b[3];
    return o;
}

// ===========================================================================
// FUSED cooperative kernel: 512 blocks x 256 thr, 2 blocks/CU (LDS 77824x2
// = 152 KiB <= 160 KiB; VGPR <= 256 at launch_bounds(256,2)), so all 512
// blocks are co-resident and grid.sync() is legal. Phases:
//   0: W fp32->bf16 (8192 threads)          | 1: QKV proj (768 units, strided)
//   2: flash attention (R2 body, bid)       | 3: out proj (512 units)
// __threadfence + grid.sync between phases gives cross-XCD visibility.
// Hypothesis under test: ~95us of the pipeline is kernel-boundary overhead,
// not GEMM work. Tripwire: fused dispatch >=135us falsifies it.
// ===========================================================================
__global__ __launch_bounds__(256, 2) void mha_fused(
    const float* __restrict__ xq, const float* __restrict__ xk, const float* __restrict__ xv,
    const float* __restrict__ Wq, const float* __restrict__ Wk, const float* __restrict__ Wv,
    const float* __restrict__ Wo,
    const float* __restrict__ bq, const float* __restrict__ bk, const float* __restrict__ bv,
    const float* __restrict__ bo,
    __bf16* __restrict__ Qs, __bf16* __restrict__ Kb, __bf16* __restrict__ Vt,
    __bf16* __restrict__ ctxb, __bf16* __restrict__ Wb, float* __restrict__ out)
{
    __shared__ __align__(16) char smem[77824];
    const int bid  = blockIdx.x;
    const int tid  = threadIdx.x;
    const int wave = tid >> 6, lane = tid & 63;
    const int quad = lane >> 4, l15 = lane & 15;

    // ---- phase 0: weight convert fp32 -> bf16 -----------------------------
    {
        const int gid = bid * 256 + tid;
        if (gid < 8192) {
            const int w = gid >> 11, off = (gid & 2047) * 8;
            const float* s = (w == 0) ? Wq : ((w == 1) ? Wk : ((w == 2) ? Wv : Wo));
            *(bf16x8*)(Wb + w * 16384 + off) = cvt8(s + off);
        }
    }
    __threadfence();
    cg::this_grid().sync();

    // ---- phase 1: fused QKV projection (768 units over 512 blocks) --------
    for (int u = bid; u < 768; u += 512) {
        const int z = u >> 8, rem = u & 255;
        const int b = rem >> 6, xc = rem & 63;
        const float* x    = (z == 0) ? xq : ((z == 1) ? xk : xv);
        const __bf16* Wf  = Wb + z * 16384;
        const float* bias = (z == 0) ? bq : ((z == 1) ? bk : bv);
        const int n0 = xc * 64 + wave * 16;

        bf16x8 a[4];
        const float* xrow = x + (b * N_SEQ + n0 + l15) * DIM + quad * 8;
        a[0] = cvt8(xrow);      a[1] = cvt8(xrow + 32);
        a[2] = cvt8(xrow + 64); a[3] = cvt8(xrow + 96);

        const int n = n0 + l15;                // D col = n (swapped)
        #pragma unroll
        for (int t = 0; t < 8; t++) {
            const __bf16* wr = Wf + (t * 16 + l15) * DIM + quad * 8;
            bf16x8 w0 = *(const bf16x8*)(wr);
            bf16x8 w1 = *(const bf16x8*)(wr + 32);
            bf16x8 w2 = *(const bf16x8*)(wr + 64);
            bf16x8 w3 = *(const bf16x8*)(wr + 96);

            f32x4 acc = {0.f, 0.f, 0.f, 0.f};
            acc = MFMA(w0, a[0], acc);
            acc = MFMA(w1, a[1], acc);
            acc = MFMA(w2, a[2], acc);
            acc = MFMA(w3, a[3], acc);

            const int d0 = t * 16 + quad * 4;  // D row = d0 + r
            if (z == 0) {
                const int h = d0 >> 5, dh0 = d0 & 31;
                bf16x4 q4;
                #pragma unroll
                for (int r = 0; r < 4; r++)
                    q4[r] = (__bf16)((acc[r] + bias[d0 + r]) * QSCALE);
                *(bf16x4*)(Qs + ((b * NH + h) * N_SEQ + n) * DH + dh0) = q4;
            } else if (z == 1) {
                const int h = d0 >> 5, dh0 = d0 & 31;
                bf16x4 k4;
                #pragma unroll
                for (int r = 0; r < 4; r++)
                    k4[r] = (__bf16)(acc[r] + bias[d0 + r]);
                *(bf16x4*)(Kb + ((b * NH + h) * N_SEQ + n) * DH + dh0) = k4;
            } else {
                const int nl = n & 63;
                const int np = (n & ~63) | (nl & 35) | ((nl & 12) << 1) | ((nl & 16) >> 2);
                #pragma unroll
                for (int r = 0; r < 4; r++) {
                    const int d = d0 + r, h = d >> 5, dh = d & 31;
                    Vt[((b * NH + h) * DH + dh) * N_SEQ + np] = (__bf16)(acc[r] + bias[d]);
                }
            }
        }
    }
    __threadfence();
    cg::this_grid().sync();

    // ---- phase 2: flash attention (exact R2 body) -------------------------
    {
        char* const Kbase = smem;              // + kh*20480 + cur*10240 + t*5120
        char* const Vbase = smem + 40960;      // + kh*18432 + cur*9216  + t*4608

        const int bh = bid & 15;
        const int qc = bid >> 4;
        const int qh = wave & 1, kh = wave >> 1;
        const int n0 = qc * 128 + qh * 64;
        const int KH = 2048;

        const __bf16* Qp = Qs + (bh * N_SEQ + n0) * DH;
        bf16x8 qf[4];
        #pragma unroll
        for (int q = 0; q < 4; q++)
            qf[q] = *(const bf16x8*)(Qp + (q * 16 + l15) * DH + quad * 8);

        bf16x8 ones;
        #pragma unroll
        for (int i = 0; i < 8; i++) ones[i] = (__bf16)1.0f;

        const int r_ = tid >> 2, c_ = tid & 3;
        const __bf16* gK = Kb + (size_t)bh * N_SEQ * DH + r_ * DH + c_ * 8;
        const __bf16* gV = Vt + ((size_t)bh * DH + (tid >> 3)) * N_SEQ + (tid & 7) * 8;
        const int kofsK = r_ * 80 + c_ * 16;
        const int kofsV = (tid >> 3) * 144 + (tid & 7) * 16;

        {   // prologue: superblock 0 of both kh groups -> buf 0
            #pragma unroll
            for (int g = 0; g < 2; g++) {
                #pragma unroll
                for (int t = 0; t < 2; t++) {
                    bf16x8 kr = *(const bf16x8*)(gK + (size_t)(g * KH + t * 64) * DH);
                    bf16x8 vr = *(const bf16x8*)(gV + g * KH + t * 64);
                    *(bf16x8*)(Kbase + g * 20480 + t * 5120 + kofsK) = kr;
                    *(bf16x8*)(Vbase + g * 18432 + t * 4608 + kofsV) = vr;
                }
            }
        }
        __syncthreads();

        char* const Kme = Kbase + kh * 20480;
        char* const Vme = Vbase + kh * 18432;

        f32x4 c[4][2];
        f32x4 cl[4];
        const f32x4 z4 = {0.f,0.f,0.f,0.f};
        #pragma unroll
        for (int q = 0; q < 4; q++) { c[q][0] = z4; c[q][1] = z4; cl[q] = z4; }

        for (int kbb = 0; kbb < KH / 128; kbb++) {
            const int cur = kbb & 1;
            const char* Kc = Kme + cur * 10240;
            const char* Vc = Vme + cur * 9216;

            const int kn = (kbb + 1) & (KH / 128 - 1);
            bf16x8 krn[2][2], vrn[2][2];
            #pragma unroll
            for (int g = 0; g < 2; g++) {
                #pragma unroll
                for (int t = 0; t < 2; t++) {
                    krn[g][t] = *(const bf16x8*)(gK + (size_t)(g * KH + kn * 128 + t * 64) * DH);
                    vrn[g][t] = *(const bf16x8*)(gV + g * KH + kn * 128 + t * 64);
                }
            }

            bf16x8 kfa[2][4], vfa[2][4];
            #pragma unroll
            for (int t = 0; t < 2; t++) {
                const char* Kt  = Kc + t * 5120;
                const char* Vtl = Vc + t * 4608;
                #pragma unroll
                for (int i = 0; i < 4; i++)
                    kfa[t][i] = *(const bf16x8*)(Kt + (i * 16 + l15) * 80 + quad * 16);
                vfa[t][0] = *(const bf16x8*)(Vtl + l15 * 144 + quad * 16);
                vfa[t][1] = *(const bf16x8*)(Vtl + (16 + l15) * 144 + quad * 16);
                vfa[t][2] = *(const bf16x8*)(Vtl + l15 * 144 + 64 + quad * 16);
                vfa[t][3] = *(const bf16x8*)(Vtl + (16 + l15) * 144 + 64 + quad * 16);
            }

            #pragma unroll
            for (int t = 0; t < 2; t++) {
                bf16x8 pf[4][2];
                #pragma unroll
                for (int q = 0; q < 4; q++) {
                    __builtin_amdgcn_s_setprio(1);
                    f32x4 sa = MFMA(kfa[t][0], qf[q], z4);
                    f32x4 sb = MFMA(kfa[t][1], qf[q], z4);
                    f32x4 sc = MFMA(kfa[t][2], qf[q], z4);
                    f32x4 sd = MFMA(kfa[t][3], qf[q], z4);
                    __builtin_amdgcn_s_setprio(0);
                    f32x4 ea = exp4(sa), eb = exp4(sb), ec = exp4(sc), ed = exp4(sd);
                    pf[q][0] = pack8(ea, eb);
                    pf[q][1] = pack8(ec, ed);
                }

                __builtin_amdgcn_s_setprio(1);
                #pragma unroll
                for (int q = 0; q < 4; q++) {
                    c[q][0] = MFMA(vfa[t][0], pf[q][0], c[q][0]);
                    c[q][1] = MFMA(vfa[t][1], pf[q][0], c[q][1]);
                    c[q][0] = MFMA(vfa[t][2], pf[q][1], c[q][0]);
                    c[q][1] = MFMA(vfa[t][3], pf[q][1], c[q][1]);
                    cl[q]   = MFMA(ones, pf[q][0], cl[q]);
                    cl[q]   = MFMA(ones, pf[q][1], cl[q]);
                }
                __builtin_amdgcn_s_setprio(0);
            }

            #pragma unroll
            for (int g = 0; g < 2; g++) {
                #pragma unroll
                for (int t = 0; t < 2; t++) {
                    *(bf16x8*)(Kbase + g * 20480 + (cur ^ 1) * 10240 + t * 5120 + kofsK) = krn[g][t];
                    *(bf16x8*)(Vbase + g * 18432 + (cur ^ 1) * 9216 + t * 4608 + kofsV) = vrn[g][t];
                }
            }
            __syncthreads();
        }

        if (kh == 1) {
            char* dst = smem + (qh * 64 + lane) * 144;
            #pragma unroll
            for (int q = 0; q < 4; q++) {
                *(f32x4*)(dst + (q * 2 + 0) * 16) = c[q][0];
                *(f32x4*)(dst + (q * 2 + 1) * 16) = c[q][1];
            }
            f32x4 lv = {cl[0][0], cl[1][0], cl[2][0], cl[3][0]};
            *(f32x4*)(dst + 128) = lv;
        }
        __syncthreads();
        if (kh == 0) {
            const char* src = smem + (qh * 64 + lane) * 144;
            f32x4 lp = *(const f32x4*)(src + 128);
            const int b = bh >> 2, h = bh & 3;
            #pragma unroll
            for (int q = 0; q < 4; q++) {
                c[q][0] += *(const f32x4*)(src + (q * 2 + 0) * 16);
                c[q][1] += *(const f32x4*)(src + (q * 2 + 1) * 16);
                const float inv = 1.0f / (cl[q][0] + lp[q]);
                const int qg = n0 + q * 16 + l15;
                __bf16* dst = ctxb + ((size_t)(b * N_SEQ + qg)) * DIM + h * DH + quad * 4;
                #pragma unroll
                for (int dt = 0; dt < 2; dt++) {
                    f32x4 cc = c[q][dt];
                    bf16x2 e0 = {(__bf16)(cc[0] * inv), (__bf16)(cc[1] * inv)};
                    bf16x2 e1 = {(__bf16)(cc[2] * inv), (__bf16)(cc[3] * inv)};
                    *(bf16x2*)(dst + dt * 16)     = e0;
                    *(bf16x2*)(dst + dt * 16 + 2) = e1;
                }
            }
        }
    }
    __threadfence();
    cg::this_grid().sync();

    // ---- phase 3: output projection (512 units: 64 rows x half-D) ---------
    {
        const int nchunk = bid >> 1, thalf = bid & 1;
        const int b = nchunk >> 6, nc = nchunk & 63;
        const int n0 = nc * 64 + wave * 16;
        const __bf16* Wf = Wb + 3 * 16384;

        bf16x8 a[4];
        const __bf16* crow = ctxb + (b * N_SEQ + n0 + l15) * DIM + quad * 8;
        a[0] = *(const bf16x8*)(crow);
        a[1] = *(const bf16x8*)(crow + 32);
        a[2] = *(const bf16x8*)(crow + 64);
        a[3] = *(const bf16x8*)(crow + 96);

        const int n = n0 + l15;
        #pragma unroll
        for (int tt = 0; tt < 4; tt++) {
            const int t = thalf * 4 + tt;
            const __bf16* wr = Wf + (t * 16 + l15) * DIM + quad * 8;
            bf16x8 w0 = *(const bf16x8*)(wr);
            bf16x8 w1 = *(const bf16x8*)(wr + 32);
            bf16x8 w2 = *(const bf16x8*)(wr + 64);
            bf16x8 w3 = *(const bf16x8*)(wr + 96);

            f32x4 acc = {0.f, 0.f, 0.f, 0.f};
            acc = MFMA(w0, a[0], acc);
            acc = MFMA(w1, a[1], acc);
            acc = MFMA(w2, a[2], acc);
            acc = MFMA(w3, a[3], acc);

            const int d0 = t * 16 + quad * 4;
            float4 o;
            o.x = acc[0] + bo[d0];
            o.y = acc[1] + bo[d0 + 1];
            o.z = acc[2] + bo[d0 + 2];
            o.w = acc[3] + bo[d0 + 3];
            *(float4*)(out + (b * N_SEQ + n) * DIM + d0) = o;
        }
    }
}

// ===========================================================================
// Fallback standalone kernels (R6 versions) — used only if the cooperative
// launch is rejected by the runtime.
// ===========================================================================
__global__ __launch_bounds__(256) void cvt_w(
    const float* __restrict__ Wq, const float* __restrict__ Wk,
    const float* __restrict__ Wv, const float* __restrict__ Wo,
    __bf16* __restrict__ Wb)
{
    const int i = blockIdx.x * 256 + threadIdx.x;
    const int w = i >> 11;
    const int off = (i & 2047) * 8;
    const float* s = (w == 0) ? Wq : ((w == 1) ? Wk : ((w == 2) ? Wv : Wo));
    *(bf16x8*)(Wb + w * 16384 + off) = cvt8(s + off);
}

__global__ __launch_bounds__(256) void proj_qkv(
    const float* __restrict__ xq, const float* __restrict__ xk, const float* __restrict__ xv,
    const __bf16* __restrict__ Wb,
    const float* __restrict__ bq, const float* __restrict__ bk, const float* __restrict__ bv,
    __bf16* __restrict__ Qs, __bf16* __restrict__ Kb, __bf16* __restrict__ Vt)
{
    const int z = blockIdx.z;
    const float* x    = (z == 0) ? xq : ((z == 1) ? xk : xv);
    const __bf16* Wf  = Wb + z * 16384;
    const float* bias = (z == 0) ? bq : ((z == 1) ? bk : bv);
    const int b    = blockIdx.y;
    const int tid  = threadIdx.x;
    const int wave = tid >> 6, lane = tid & 63;
    const int quad = lane >> 4, l15 = lane & 15;
    const int n0   = blockIdx.x * 64 + wave * 16;

    bf16x8 a[4];
    const float* xrow = x + (b * N_SEQ + n0 + l15) * DIM + quad * 8;
    a[0] = cvt8(xrow);      a[1] = cvt8(xrow + 32);
    a[2] = cvt8(xrow + 64); a[3] = cvt8(xrow + 96);

    const int n = n0 + l15;
    #pragma unroll
    for (int t = 0; t < 8; t++) {
        const __bf16* wr = Wf + (t * 16 + l15) * DIM + quad * 8;
        bf16x8 w0 = *(const bf16x8*)(wr);
        bf16x8 w1 = *(const bf16x8*)(wr + 32);
        bf16x8 w2 = *(const bf16x8*)(wr + 64);
        bf16x8 w3 = *(const bf16x8*)(wr + 96);

        f32x4 acc = {0.f, 0.f, 0.f, 0.f};
        acc = MFMA(w0, a[0], acc);
        acc = MFMA(w1, a[1], acc);
        acc = MFMA(w2, a[2], acc);
        acc = MFMA(w3, a[3], acc);

        const int d0 = t * 16 + quad * 4;
        if (z == 0) {
            const int h = d0 >> 5, dh0 = d0 & 31;
            bf16x4 q4;
            #pragma unroll
            for (int r = 0; r < 4; r++)
                q4[r] = (__bf16)((acc[r] + bias[d0 + r]) * QSCALE);
            *(bf16x4*)(Qs + ((b * NH + h) * N_SEQ + n) * DH + dh0) = q4;
        } else if (z == 1) {
            const int h = d0 >> 5, dh0 = d0 & 31;
            bf16x4 k4;
            #pragma unroll
            for (int r = 0; r < 4; r++)
                k4[r] = (__bf16)(acc[r] + bias[d0 + r]);
            *(bf16x4*)(Kb + ((b * NH + h) * N_SEQ + n) * DH + dh0) = k4;
        } else {
            const int nl = n & 63;
            const int np = (n & ~63) | (nl & 35) | ((nl & 12) << 1) | ((nl & 16) >> 2);
            #pragma unroll
            for (int r = 0; r < 4; r++) {
                const int d = d0 + r, h = d >> 5, dh = d & 31;
                Vt[((b * NH + h) * DH + dh) * N_SEQ + np] = (__bf16)(acc[r] + bias[d]);
            }
        }
    }
}

__global__ __launch_bounds__(256, 2) void flash_attn(
    const __bf16* __restrict__ Qs, const __bf16* __restrict__ Kb,
    const __bf16* __restrict__ Vt, __bf16* __restrict__ ctxb)
{
    __shared__ __align__(16) char smem[77824];
    char* const Kbase = smem;
    char* const Vbase = smem + 40960;

    const int bid  = blockIdx.x;
    const int bh   = bid & 15;
    const int qc   = bid >> 4;
    const int tid  = threadIdx.x;
    const int wave = tid >> 6, lane = tid & 63;
    const int quad = lane >> 4, l15 = lane & 15;
    const int qh   = wave & 1, kh = wave >> 1;
    const int n0   = qc * 128 + qh * 64;
    const int KH   = 2048;

    const __bf16* Qp = Qs + (bh * N_SEQ + n0) * DH;
    bf16x8 qf[4];
    #pragma unroll
    for (int q = 0; q < 4; q++)
        qf[q] = *(const bf16x8*)(Qp + (q * 16 + l15) * DH + quad * 8);

    bf16x8 ones;
    #pragma unroll
    for (int i = 0; i < 8; i++) ones[i] = (__bf16)1.0f;

    const int r_ = tid >> 2, c_ = tid & 3;
    const __bf16* gK = Kb + (size_t)bh * N_SEQ * DH + r_ * DH + c_ * 8;
    const __bf16* gV = Vt + ((size_t)bh * DH + (tid >> 3)) * N_SEQ + (tid & 7) * 8;
    const int kofsK = r_ * 80 + c_ * 16;
    const int kofsV = (tid >> 3) * 144 + (tid & 7) * 16;

    {
        #pragma unroll
        for (int g = 0; g < 2; g++) {
            #pragma unroll
            for (int t = 0; t < 2; t++) {
                bf16x8 kr = *(const bf16x8*)(gK + (size_t)(g * KH + t * 64) * DH);
                bf16x8 vr = *(const bf16x8*)(gV + g * KH + t * 64);
                *(bf16x8*)(Kbase + g * 20480 + t * 5120 + kofsK) = kr;
                *(bf16x8*)(Vbase + g * 18432 + t * 4608 + kofsV) = vr;
            }
        }
    }
    __syncthreads();

    char* const Kme = Kbase + kh * 20480;
    char* const Vme = Vbase + kh * 18432;

    f32x4 c[4][2];
    f32x4 cl[4];
    const f32x4 z4 = {0.f,0.f,0.f,0.f};
    #pragma unroll
    for (int q = 0; q < 4; q++) { c[q][0] = z4; c[q][1] = z4; cl[q] = z4; }

    for (int kbb = 0; kbb < KH / 128; kbb++) {
        const int cur = kbb & 1;
        const char* Kc = Kme + cur * 10240;
        const char* Vc = Vme + cur * 9216;

        const int kn = (kbb + 1) & (KH / 128 - 1);
        bf16x8 krn[2][2], vrn[2][2];
        #pragma unroll
        for (int g = 0; g < 2; g++) {
            #pragma unroll
            for (int t = 0; t < 2; t++) {
                krn[g][t] = *(const bf16x8*)(gK + (size_t)(g * KH + kn * 128 + t * 64) * DH);
                vrn[g][t] = *(const bf16x8*)(gV + g * KH + kn * 128 + t * 64);
            }
        }

        bf16x8 kfa[2][4], vfa[2][4];
        #pragma unroll
        for (int t = 0; t < 2; t++) {
            const char* Kt  = Kc + t * 5120;
            const char* Vtl = Vc + t * 4608;
            #pragma unroll
            for (int i = 0; i < 4; i++)
                kfa[t][i] = *(const bf16x8*)(Kt + (i * 16 + l15) * 80 + quad * 16);
            vfa[t][0] = *(const bf16x8*)(Vtl + l15 * 144 + quad * 16);
            vfa[t][1] = *(const bf16x8*)(Vtl + (16 + l15) * 144 + quad * 16);
            vfa[t][2] = *(const bf16x8*)(Vtl + l15 * 144 + 64 + quad * 16);
            vfa[t][3] = *(const bf16x8*)(Vtl + (16 + l15) * 144 + 64 + quad * 16);
        }

        #pragma unroll
        for (int t = 0; t < 2; t++) {
            bf16x8 pf[4][2];
            #pragma unroll
            for (int q = 0; q < 4; q++) {
                __builtin_amdgcn_s_setprio(1);
                f32x4 sa = MFMA(kfa[t][0], qf[q], z4);
                f32x4 sb = MFMA(kfa[t][1], qf[q], z4);
                f32x4 sc = MFMA(kfa[t][2], qf[q], z4);
                f32x4 sd = MFMA(kfa[t][3], qf[q], z4);
                __builtin_amdgcn_s_setprio(0);
                f32x4 ea = exp4(sa), eb = exp4(sb), ec = exp4(sc), ed = exp4(sd);
                pf[q][0] = pack8(ea, eb);
                pf[q][1] = pack8(ec, ed);
            }

            __builtin_amdgcn_s_setprio(1);
            #pragma unroll
            for (int q = 0; q < 4; q++) {
                c[q][0] = MFMA(vfa[t][0], pf[q][0], c[q][0]);
                c[q][1] = MFMA(vfa[t][1], pf[q][0], c[q][1]);
                c[q][0] = MFMA(vfa[t][2], pf[q][1], c[q][0]);
                c[q][1] = MFMA(vfa[t][3], pf[q][1], c[q][1]);
                cl[q]   = MFMA(ones, pf[q][0], cl[q]);
                cl[q]   = MFMA(ones, pf[q][1], cl[q]);
            }
            __builtin_amdgcn_s_setprio(0);
        }

        #pragma unroll
        for (int g = 0; g < 2; g++) {
            #pragma unroll
            for (int t = 0; t < 2; t++) {
                *(bf16x8*)(Kbase + g * 20480 + (cur ^ 1) * 10240 + t * 5120 + kofsK) = krn[g][t];
                *(bf16x8*)(Vbase + g * 18432 + (cur ^ 1) * 9216 + t * 4608 + kofsV) = vrn[g][t];
            }
        }
        __syncthreads();
    }

    if (kh == 1) {
        char* dst = smem + (qh * 64 + lane) * 144;
        #pragma unroll
        for (int q = 0; q < 4; q++) {
            *(f32x4*)(dst + (q * 2 + 0) * 16) = c[q][0];
            *(f32x4*)(dst + (q * 2 + 1) * 16) = c[q][1];
        }
        f32x4 lv = {cl[0][0], cl[1][0], cl[2][0], cl[3][0]};
        *(f32x4*)(dst + 128) = lv;
    }
    __syncthreads();
    if (kh == 0) {
        const char* src = smem + (qh * 64 + lane) * 144;
        f32x4 lp = *(const f32x4*)(src + 128);
        const int b = bh >> 2, h = bh & 3;
        #pragma unroll
        for (int q = 0; q < 4; q++) {
            c[q][0] += *(const f32x4*)(src + (q * 2 + 0) * 16);
            c[q][1] += *(const f32x4*)(src + (q * 2 + 1) * 16);
            const float inv = 1.0f / (cl[q][0] + lp[q]);
            const int qg = n0 + q * 16 + l15;
            __bf16* dst = ctxb + ((size_t)(b * N_SEQ + qg)) * DIM + h * DH + quad * 4;
            #pragma unroll
            for (int dt = 0; dt < 2; dt++) {
                f32x4 cc = c[q][dt];
                bf16x2 e0 = {(__bf16)(cc[0] * inv), (__bf16)(cc[1] * inv)};
                bf16x2 e1 = {(__bf16)(cc[2] * inv), (__bf16)(cc[3] * inv)};
                *(bf16x2*)(dst + dt * 16)     = e0;
                *(bf16x2*)(dst + dt * 16 + 2) = e1;
            }
        }
    }
}

__global__ __launch_bounds__(256) void out_proj(
    const __bf16* __restrict__ ctxb, const __bf16* __restrict__ Wb,
    const float* __restrict__ bo, float* __restrict__ out)
{
    const __bf16* Wf = Wb + 3 * 16384;
    const int b    = blockIdx.y;
    const int tid  = threadIdx.x;
    const int wave = tid >> 6, lane = tid & 63;
    const int quad = lane >> 4, l15 = lane & 15;
    const int n0   = blockIdx.x * 64 + wave * 16;

    bf16x8 a[4];
    const __bf16* crow = ctxb + (b * N_SEQ + n0 + l15) * DIM + quad * 8;
    a[0] = *(const bf16x8*)(crow);
    a[1] = *(const bf16x8*)(crow + 32);
    a[2] = *(const bf16x8*)(crow + 64);
    a[3] = *(const bf16x8*)(crow + 96);

    const int n = n0 + l15;
    #pragma unroll
    for (int t = 0; t < 8; t++) {
        const __bf16* wr = Wf + (t * 16 + l15) * DIM + quad * 8;
        bf16x8 w0 = *(const bf16x8*)(wr);
        bf16x8 w1 = *(const bf16x8*)(wr + 32);
        bf16x8 w2 = *(const bf16x8*)(wr + 64);
        bf16x8 w3 = *(const bf16x8*)(wr + 96);

        f32x4 acc = {0.f, 0.f, 0.f, 0.f};
        acc = MFMA(w0, a[0], acc);
        acc = MFMA(w1, a[1], acc);
        acc = MFMA(w2, a[2], acc);
        acc = MFMA(w3, a[3], acc);

        const int d0 = t * 16 + quad * 4;
        float4 o;
        o.x = acc[0] + bo[d0];
        o.y = acc[1] + bo[d0 + 1];
        o.z = acc[2] + bo[d0 + 2];
        o.w = acc[3] + bo[d0 + 3];
        *(float4*)(out + (b * N_SEQ + n) * DIM + d0) = o;
    }
}

// ---------------------------------------------------------------------------
extern "C" void kernel_launch(void* const* d_in, const int* in_sizes, int n_in,
                              void* d_out, int out_size, void* d_ws, size_t ws_size,
                              hipStream_t stream)
{
    const float* query = (const float*)d_in[0];
    const float* key   = (const float*)d_in[1];
    const float* value = (const float*)d_in[2];
    const float* Wq = (const float*)d_in[3];
    const float* bq = (const float*)d_in[4];
    const float* Wk = (const float*)d_in[5];
    const float* bk = (const float*)d_in[6];
    const float* Wv = (const float*)d_in[7];
    const float* bv = (const float*)d_in[8];
    const float* Wo = (const float*)d_in[9];
    const float* bo = (const float*)d_in[10];
    float* out = (float*)d_out;

    char* ws = (char*)d_ws;
    const size_t e = (size_t)BATCH * N_SEQ * DIM;   // 2,097,152 elements
    __bf16* Qs   = (__bf16*)(ws);                   // 4 MB  [B,H,N,32] scaled
    __bf16* Kb   = (__bf16*)(ws + 2 * e);           // 4 MB  [B,H,N,32] identity
    __bf16* Vt   = (__bf16*)(ws + 4 * e);           // 4 MB  [B,H,32,N] key-permuted
    __bf16* ctxb = (__bf16*)(ws + 6 * e);           // 4 MB  [B,N,128]
    __bf16* Wbf  = (__bf16*)(ws + 8 * e);           // 128 KB [4][128*128] bf16

    void* args[] = {
        (void*)&query, (void*)&key, (void*)&value,
        (void*)&Wq, (void*)&Wk, (void*)&Wv, (void*)&Wo,
        (void*)&bq, (void*)&bk, (void*)&bv, (void*)&bo,
        (void*)&Qs, (void*)&Kb, (void*)&Vt, (void*)&ctxb, (void*)&Wbf,
        (void*)&out
    };
    hipError_t err = hipLaunchCooperativeKernel(
        (const void*)mha_fused, dim3(512), dim3(256), args, 0, stream);

    if (err != hipSuccess) {
        // fallback: 4-kernel sequence (R6 structure)
        cvt_w<<<dim3(32), 256, 0, stream>>>(Wq, Wk, Wv, Wo, Wbf);
        proj_qkv<<<dim3(64, BATCH, 3), 256, 0, stream>>>(
            query, key, value, Wbf, bq, bk, bv, Qs, Kb, Vt);
        flash_attn<<<dim3(512), 256, 0, stream>>>(Qs, Kb, Vt, ctxb);
        out_proj<<<dim3(64, BATCH), 256, 0, stream>>>(ctxb, Wbf, bo, out);
    }
}

// Round 8
// 146.560 us; speedup vs baseline: 3.3156x; 3.3156x over previous
//
#include <hip/hip_runtime.h>
#include <hip/hip_bf16.h>

#define N_SEQ 4096
#define DIM   128
#define NH    4
#define DH    32
#define BATCH 4

// scale = (1/sqrt(32)) * log2(e): softmax computed in exp2 domain
#define QSCALE 0.25503495870989204f

typedef __bf16 bf16x8 __attribute__((ext_vector_type(8)));
typedef __bf16 bf16x2 __attribute__((ext_vector_type(2)));
typedef __bf16 bf16x4 __attribute__((ext_vector_type(4)));
typedef float  f32x4  __attribute__((ext_vector_type(4)));

#define MFMA(a, b, c) __builtin_amdgcn_mfma_f32_16x16x32_bf16((a), (b), (c), 0, 0, 0)

static __device__ __forceinline__ bf16x8 cvt8(const float* __restrict__ p) {
    const float4* f4 = reinterpret_cast<const float4*>(p);
    float4 a = f4[0], b = f4[1];
    bf16x8 r;
    r[0] = (__bf16)a.x; r[1] = (__bf16)a.y; r[2] = (__bf16)a.z; r[3] = (__bf16)a.w;
    r[4] = (__bf16)b.x; r[5] = (__bf16)b.y; r[6] = (__bf16)b.z; r[7] = (__bf16)b.w;
    return r;
}

static __device__ __forceinline__ f32x4 exp4(f32x4 s) {
    f32x4 r;
    r[0] = __builtin_amdgcn_exp2f(s[0]);
    r[1] = __builtin_amdgcn_exp2f(s[1]);
    r[2] = __builtin_amdgcn_exp2f(s[2]);
    r[3] = __builtin_amdgcn_exp2f(s[3]);
    return r;
}

// adjacent-pair writes -> compiler can fuse into packed bf16 converts
static __device__ __forceinline__ bf16x8 pack8(f32x4 a, f32x4 b) {
    bf16x8 o;
    o[0] = (__bf16)a[0]; o[1] = (__bf16)a[1];
    o[2] = (__bf16)a[2]; o[3] = (__bf16)a[3];
    o[4] = (__bf16)b[0]; o[5] = (__bf16)b[1];
    o[6] = (__bf16)b[2]; o[7] = (__bf16)b[3];
    return o;
}

// ---------------------------------------------------------------------------
// Kernel 1: fused QKV projection, operand-SWAPPED MFMA (A=W rows, B=x rows).
// (R2 revert — held control; per-block LDS W staging beat cvt_w + direct-W
// by ~7 µs in R6, and R7 proved proj is already near-roofline.)
// ---------------------------------------------------------------------------
__global__ __launch_bounds__(256) void proj_qkv(
    const float* __restrict__ xq, const float* __restrict__ xk, const float* __restrict__ xv,
    const float* __restrict__ Wq, const float* __restrict__ Wk, const float* __restrict__ Wv,
    const float* __restrict__ bq, const float* __restrict__ bk, const float* __restrict__ bv,
    __bf16* __restrict__ Qs, __bf16* __restrict__ Kb, __bf16* __restrict__ Vt)
{
    __shared__ __align__(16) char wlds[34816];        // 128 rows x 272 B
    const int z = blockIdx.z;
    const float* x    = (z == 0) ? xq : ((z == 1) ? xk : xv);
    const float* Wf   = (z == 0) ? Wq : ((z == 1) ? Wk : Wv);
    const float* bias = (z == 0) ? bq : ((z == 1) ? bk : bv);
    const int b    = blockIdx.y;
    const int tid  = threadIdx.x;
    const int wave = tid >> 6, lane = tid & 63;
    const int quad = lane >> 4, l15 = lane & 15;
    const int n0   = blockIdx.x * 64 + wave * 16;

    {   // stage W (fp32 -> bf16) into LDS: thread = half-row
        const int r = tid >> 1, half = tid & 1;
        const float* wsrc = Wf + r * DIM + half * 64;
        char* wdst = wlds + r * 272 + half * 128;
        #pragma unroll
        for (int i = 0; i < 8; i++)
            *(bf16x8*)(wdst + i * 16) = cvt8(wsrc + i * 8);
    }

    bf16x8 a[4];
    const float* xrow = x + (b * N_SEQ + n0 + l15) * DIM + quad * 8;
    a[0] = cvt8(xrow);      a[1] = cvt8(xrow + 32);
    a[2] = cvt8(xrow + 64); a[3] = cvt8(xrow + 96);
    __syncthreads();

    const int n = n0 + l15;                    // D col = n (swapped)
    for (int t = 0; t < 8; t++) {
        const char* wr = wlds + (t * 16 + l15) * 272 + quad * 16;
        bf16x8 w0 = *(const bf16x8*)(wr);
        bf16x8 w1 = *(const bf16x8*)(wr + 64);
        bf16x8 w2 = *(const bf16x8*)(wr + 128);
        bf16x8 w3 = *(const bf16x8*)(wr + 192);

        f32x4 acc = {0.f, 0.f, 0.f, 0.f};
        acc = MFMA(w0, a[0], acc);
        acc = MFMA(w1, a[1], acc);
        acc = MFMA(w2, a[2], acc);
        acc = MFMA(w3, a[3], acc);

        const int d0 = t * 16 + quad * 4;      // D row = d0 + r
        if (z == 0) {
            const int h = d0 >> 5, dh0 = d0 & 31;
            bf16x4 q4;
            #pragma unroll
            for (int r = 0; r < 4; r++)
                q4[r] = (__bf16)((acc[r] + bias[d0 + r]) * QSCALE);
            *(bf16x4*)(Qs + ((b * NH + h) * N_SEQ + n) * DH + dh0) = q4;
        } else if (z == 1) {
            const int h = d0 >> 5, dh0 = d0 & 31;
            bf16x4 k4;
            #pragma unroll
            for (int r = 0; r < 4; r++)
                k4[r] = (__bf16)(acc[r] + bias[d0 + r]);
            *(bf16x4*)(Kb + ((b * NH + h) * N_SEQ + n) * DH + dh0) = k4;
        } else {
            const int nl = n & 63;
            const int np = (n & ~63) | (nl & 35) | ((nl & 12) << 1) | ((nl & 16) >> 2);
            #pragma unroll
            for (int r = 0; r < 4; r++) {
                const int d = d0 + r, h = d >> 5, dh = d & 31;
                Vt[((b * NH + h) * DH + dh) * N_SEQ + np] = (__bf16)(acc[r] + bias[d]);
            }
        }
    }
}

// ---------------------------------------------------------------------------
// Kernel 2: attention — R2 structure + PHASE-REORDERED inner tile.
// R7 established: harness fixed overhead ~90 us; flash is the only real
// target. R2's issue order (per q: 4 S-MFMA -> stall -> 16 exp) starves
// the TRANS pipe whenever both waves sit in S->exp waits. New order per
// 64-key tile: ALL 16 S-MFMAs (4q x 4 frags) -> ALL 64 exps -> PV.
// First exp waits on MFMA 1-of-16 instead of 1-of-4, and the wider MFMA
// phase overlaps the sibling wave's TRANS phase. Scores held in s[4][4]
// (static indices, +48 VGPR transient, ~180 peak < 256 cap @ 2 blk/CU).
// Everything else identical to R2 (best measured: 50.4 us).
// ---------------------------------------------------------------------------
__global__ __launch_bounds__(256, 2) void flash_attn(
    const __bf16* __restrict__ Qs, const __bf16* __restrict__ Kb,
    const __bf16* __restrict__ Vt, __bf16* __restrict__ ctxb)
{
    // K: 2 kh x 2 buf x 2 tiles x 5120 = 40960
    // V: 2 kh x 2 buf x 2 tiles x 4608 = 36864
    __shared__ __align__(16) char smem[77824];
    char* const Kbase = smem;                  // + kh*20480 + cur*10240 + t*5120
    char* const Vbase = smem + 40960;          // + kh*18432 + cur*9216  + t*4608

    const int bid  = blockIdx.x;
    const int bh   = bid & 15;                 // consecutive blocks cycle heads
    const int qc   = bid >> 4;                 // 0..31, 128 queries each
    const int tid  = threadIdx.x;
    const int wave = tid >> 6, lane = tid & 63;
    const int quad = lane >> 4, l15 = lane & 15;
    const int qh   = wave & 1, kh = wave >> 1; // kh in {0,1}
    const int n0   = qc * 128 + qh * 64;
    const int KH   = 2048;                     // keys per kh

    // Q B-fragments: 4 tiles of 16 queries
    const __bf16* Qp = Qs + (bh * N_SEQ + n0) * DH;
    bf16x8 qf[4];
    #pragma unroll
    for (int q = 0; q < 4; q++)
        qf[q] = *(const bf16x8*)(Qp + (q * 16 + l15) * DH + quad * 8);

    // ones A-fragment for the l-sum MFMA (l = 1*P summed over frag keys)
    bf16x8 ones;
    #pragma unroll
    for (int i = 0; i < 8; i++) ones[i] = (__bf16)1.0f;

    // staging: thread covers one 16B chunk of each tile (4 K + 4 V per superblock)
    const int r_ = tid >> 2, c_ = tid & 3;
    const __bf16* gK = Kb + (size_t)bh * N_SEQ * DH + r_ * DH + c_ * 8;
    const __bf16* gV = Vt + ((size_t)bh * DH + (tid >> 3)) * N_SEQ + (tid & 7) * 8;
    const int kofsK = r_ * 80 + c_ * 16;
    const int kofsV = (tid >> 3) * 144 + (tid & 7) * 16;

    {   // prologue: superblock 0 (2 tiles) of both kh groups -> buf 0
        #pragma unroll
        for (int g = 0; g < 2; g++) {
            #pragma unroll
            for (int t = 0; t < 2; t++) {
                bf16x8 kr = *(const bf16x8*)(gK + (size_t)(g * KH + t * 64) * DH);
                bf16x8 vr = *(const bf16x8*)(gV + g * KH + t * 64);
                *(bf16x8*)(Kbase + g * 20480 + t * 5120 + kofsK) = kr;
                *(bf16x8*)(Vbase + g * 18432 + t * 4608 + kofsV) = vr;
            }
        }
    }
    __syncthreads();

    char* const Kme = Kbase + kh * 20480;
    char* const Vme = Vbase + kh * 18432;

    f32x4 c[4][2];
    f32x4 cl[4];
    const f32x4 z4 = {0.f,0.f,0.f,0.f};
    #pragma unroll
    for (int q = 0; q < 4; q++) { c[q][0] = z4; c[q][1] = z4; cl[q] = z4; }

    for (int kbb = 0; kbb < KH / 128; kbb++) { // 16 superblocks, 1 barrier each
        const int cur = kbb & 1;
        const char* Kc = Kme + cur * 10240;
        const char* Vc = Vme + cur * 9216;

        // prefetch next superblock for both kh groups (wraps; harmless)
        const int kn = (kbb + 1) & (KH / 128 - 1);
        bf16x8 krn[2][2], vrn[2][2];
        #pragma unroll
        for (int g = 0; g < 2; g++) {
            #pragma unroll
            for (int t = 0; t < 2; t++) {
                krn[g][t] = *(const bf16x8*)(gK + (size_t)(g * KH + kn * 128 + t * 64) * DH);
                vrn[g][t] = *(const bf16x8*)(gV + g * KH + kn * 128 + t * 64);
            }
        }

        // hoist ALL fragment ds_reads for BOTH 64-key tiles up front:
        // tile1's LDS latency hides under tile0's full compute chain.
        bf16x8 kfa[2][4], vfa[2][4];
        #pragma unroll
        for (int t = 0; t < 2; t++) {
            const char* Kt  = Kc + t * 5120;
            const char* Vtl = Vc + t * 4608;
            #pragma unroll
            for (int i = 0; i < 4; i++)
                kfa[t][i] = *(const bf16x8*)(Kt + (i * 16 + l15) * 80 + quad * 16);
            vfa[t][0] = *(const bf16x8*)(Vtl + l15 * 144 + quad * 16);
            vfa[t][1] = *(const bf16x8*)(Vtl + (16 + l15) * 144 + quad * 16);
            vfa[t][2] = *(const bf16x8*)(Vtl + l15 * 144 + 64 + quad * 16);
            vfa[t][3] = *(const bf16x8*)(Vtl + (16 + l15) * 144 + 64 + quad * 16);
        }

        #pragma unroll
        for (int t = 0; t < 2; t++) {          // two 64-key tiles, no barrier between
            // ---- phase A: ALL 16 S-MFMAs of this tile (deep MFMA queue) ----
            f32x4 s[4][4];
            __builtin_amdgcn_s_setprio(1);
            #pragma unroll
            for (int q = 0; q < 4; q++) {
                s[q][0] = MFMA(kfa[t][0], qf[q], z4);
                s[q][1] = MFMA(kfa[t][1], qf[q], z4);
                s[q][2] = MFMA(kfa[t][2], qf[q], z4);
                s[q][3] = MFMA(kfa[t][3], qf[q], z4);
            }
            __builtin_amdgcn_s_setprio(0);

            // ---- phase B: all 64 exps + pack (TRANS burst) -----------------
            bf16x8 pf[4][2];
            #pragma unroll
            for (int q = 0; q < 4; q++) {
                f32x4 ea = exp4(s[q][0]), eb = exp4(s[q][1]);
                f32x4 ec = exp4(s[q][2]), ed = exp4(s[q][3]);
                pf[q][0] = pack8(ea, eb);      // keys g0
                pf[q][1] = pack8(ec, ed);      // keys g1
            }

            // ---- phase C: PV + l-sum (MFMA burst) --------------------------
            __builtin_amdgcn_s_setprio(1);
            #pragma unroll
            for (int q = 0; q < 4; q++) {
                c[q][0] = MFMA(vfa[t][0], pf[q][0], c[q][0]);
                c[q][1] = MFMA(vfa[t][1], pf[q][0], c[q][1]);
                c[q][0] = MFMA(vfa[t][2], pf[q][1], c[q][0]);
                c[q][1] = MFMA(vfa[t][3], pf[q][1], c[q][1]);
                cl[q]   = MFMA(ones, pf[q][0], cl[q]);   // l-sum on MFMA pipe
                cl[q]   = MFMA(ones, pf[q][1], cl[q]);
            }
            __builtin_amdgcn_s_setprio(0);
        }

        // stage next superblock into the other buffer
        #pragma unroll
        for (int g = 0; g < 2; g++) {
            #pragma unroll
            for (int t = 0; t < 2; t++) {
                *(bf16x8*)(Kbase + g * 20480 + (cur ^ 1) * 10240 + t * 5120 + kofsK) = krn[g][t];
                *(bf16x8*)(Vbase + g * 18432 + (cur ^ 1) * 9216 + t * 4608 + kofsV) = vrn[g][t];
            }
        }
        __syncthreads();
    }

    // split-K combine via the dead K LDS region
    if (kh == 1) {
        char* dst = smem + (qh * 64 + lane) * 144;
        #pragma unroll
        for (int q = 0; q < 4; q++) {
            *(f32x4*)(dst + (q * 2 + 0) * 16) = c[q][0];
            *(f32x4*)(dst + (q * 2 + 1) * 16) = c[q][1];
        }
        f32x4 lv = {cl[0][0], cl[1][0], cl[2][0], cl[3][0]};
        *(f32x4*)(dst + 128) = lv;
    }
    __syncthreads();
    if (kh == 0) {
        const char* src = smem + (qh * 64 + lane) * 144;
        f32x4 lp = *(const f32x4*)(src + 128);
        const int b = bh >> 2, h = bh & 3;
        #pragma unroll
        for (int q = 0; q < 4; q++) {
            c[q][0] += *(const f32x4*)(src + (q * 2 + 0) * 16);
            c[q][1] += *(const f32x4*)(src + (q * 2 + 1) * 16);
            const float inv = 1.0f / (cl[q][0] + lp[q]);
            const int qg = n0 + q * 16 + l15;
            __bf16* dst = ctxb + ((size_t)(b * N_SEQ + qg)) * DIM + h * DH + quad * 4;
            #pragma unroll
            for (int dt = 0; dt < 2; dt++) {
                f32x4 cc = c[q][dt];
                bf16x2 e0 = {(__bf16)(cc[0] * inv), (__bf16)(cc[1] * inv)};
                bf16x2 e1 = {(__bf16)(cc[2] * inv), (__bf16)(cc[3] * inv)};
                *(bf16x2*)(dst + dt * 16)     = e0;
                *(bf16x2*)(dst + dt * 16 + 2) = e1;
            }
        }
    }
}

// ---------------------------------------------------------------------------
// Kernel 3: output projection, operand-swapped + Wo staged in LDS.
// (R2 revert — held control)
// ---------------------------------------------------------------------------
__global__ __launch_bounds__(256) void out_proj(
    const __bf16* __restrict__ ctxb, const float* __restrict__ Wo,
    const float* __restrict__ bo, float* __restrict__ out)
{
    __shared__ __align__(16) char wlds[34816];
    const int b    = blockIdx.y;
    const int tid  = threadIdx.x;
    const int wave = tid >> 6, lane = tid & 63;
    const int quad = lane >> 4, l15 = lane & 15;
    const int n0   = blockIdx.x * 64 + wave * 16;

    {   // stage Wo (fp32 -> bf16) into LDS
        const int r = tid >> 1, half = tid & 1;
        const float* wsrc = Wo + r * DIM + half * 64;
        char* wdst = wlds + r * 272 + half * 128;
        #pragma unroll
        for (int i = 0; i < 8; i++)
            *(bf16x8*)(wdst + i * 16) = cvt8(wsrc + i * 8);
    }

    bf16x8 a[4];
    const __bf16* crow = ctxb + (b * N_SEQ + n0 + l15) * DIM + quad * 8;
    a[0] = *(const bf16x8*)(crow);
    a[1] = *(const bf16x8*)(crow + 32);
    a[2] = *(const bf16x8*)(crow + 64);
    a[3] = *(const bf16x8*)(crow + 96);
    __syncthreads();

    const int n = n0 + l15;
    for (int t = 0; t < 8; t++) {
        const char* wr = wlds + (t * 16 + l15) * 272 + quad * 16;
        bf16x8 w0 = *(const bf16x8*)(wr);
        bf16x8 w1 = *(const bf16x8*)(wr + 64);
        bf16x8 w2 = *(const bf16x8*)(wr + 128);
        bf16x8 w3 = *(const bf16x8*)(wr + 192);

        f32x4 acc = {0.f, 0.f, 0.f, 0.f};
        acc = MFMA(w0, a[0], acc);
        acc = MFMA(w1, a[1], acc);
        acc = MFMA(w2, a[2], acc);
        acc = MFMA(w3, a[3], acc);

        const int d0 = t * 16 + quad * 4;
        float4 o;
        o.x = acc[0] + bo[d0];
        o.y = acc[1] + bo[d0 + 1];
        o.z = acc[2] + bo[d0 + 2];
        o.w = acc[3] + bo[d0 + 3];
        *(float4*)(out + (b * N_SEQ + n) * DIM + d0) = o;
    }
}

// ---------------------------------------------------------------------------
extern "C" void kernel_launch(void* const* d_in, const int* in_sizes, int n_in,
                              void* d_out, int out_size, void* d_ws, size_t ws_size,
                              hipStream_t stream)
{
    const float* query = (const float*)d_in[0];
    const float* key   = (const float*)d_in[1];
    const float* value = (const float*)d_in[2];
    const float* Wq = (const float*)d_in[3];
    const float* bq = (const float*)d_in[4];
    const float* Wk = (const float*)d_in[5];
    const float* bk = (const float*)d_in[6];
    const float* Wv = (const float*)d_in[7];
    const float* bv = (const float*)d_in[8];
    const float* Wo = (const float*)d_in[9];
    const float* bo = (const float*)d_in[10];
    float* out = (float*)d_out;

    char* ws = (char*)d_ws;
    const size_t e = (size_t)BATCH * N_SEQ * DIM;   // 2,097,152 elements
    __bf16* Qs   = (__bf16*)(ws);                   // 4 MB  [B,H,N,32] scaled
    __bf16* Kb   = (__bf16*)(ws + 2 * e);           // 4 MB  [B,H,N,32] identity
    __bf16* Vt   = (__bf16*)(ws + 4 * e);           // 4 MB  [B,H,32,N] key-permuted
    __bf16* ctxb = (__bf16*)(ws + 6 * e);           // 4 MB  [B,N,128]

    proj_qkv<<<dim3(64, BATCH, 3), 256, 0, stream>>>(
        query, key, value, Wq, Wk, Wv, bq, bk, bv, Qs, Kb, Vt);
    flash_attn<<<dim3(512), 256, 0, stream>>>(Qs, Kb, Vt, ctxb);
    out_proj<<<dim3(64, BATCH), 256, 0, stream>>>(ctxb, Wo, bo, out);
}

// Round 9
// 146.260 us; speedup vs baseline: 3.3224x; 1.0020x over previous
//
#include <hip/hip_runtime.h>
#include <hip/hip_bf16.h>

#define N_SEQ 4096
#define DIM   128
#define NH    4
#define DH    32
#define BATCH 4

// scale = (1/sqrt(32)) * log2(e): softmax computed in exp2 domain
#define QSCALE 0.25503495870989204f

typedef __bf16 bf16x8 __attribute__((ext_vector_type(8)));
typedef __bf16 bf16x2 __attribute__((ext_vector_type(2)));
typedef __bf16 bf16x4 __attribute__((ext_vector_type(4)));
typedef float  f32x4  __attribute__((ext_vector_type(4)));

#define MFMA(a, b, c) __builtin_amdgcn_mfma_f32_16x16x32_bf16((a), (b), (c), 0, 0, 0)

static __device__ __forceinline__ bf16x8 cvt8(const float* __restrict__ p) {
    const float4* f4 = reinterpret_cast<const float4*>(p);
    float4 a = f4[0], b = f4[1];
    bf16x8 r;
    r[0] = (__bf16)a.x; r[1] = (__bf16)a.y; r[2] = (__bf16)a.z; r[3] = (__bf16)a.w;
    r[4] = (__bf16)b.x; r[5] = (__bf16)b.y; r[6] = (__bf16)b.z; r[7] = (__bf16)b.w;
    return r;
}

static __device__ __forceinline__ f32x4 exp4(f32x4 s) {
    f32x4 r;
    r[0] = __builtin_amdgcn_exp2f(s[0]);
    r[1] = __builtin_amdgcn_exp2f(s[1]);
    r[2] = __builtin_amdgcn_exp2f(s[2]);
    r[3] = __builtin_amdgcn_exp2f(s[3]);
    return r;
}

// adjacent-pair writes -> compiler can fuse into packed bf16 converts
static __device__ __forceinline__ bf16x8 pack8(f32x4 a, f32x4 b) {
    bf16x8 o;
    o[0] = (__bf16)a[0]; o[1] = (__bf16)a[1];
    o[2] = (__bf16)a[2]; o[3] = (__bf16)a[3];
    o[4] = (__bf16)b[0]; o[5] = (__bf16)b[1];
    o[6] = (__bf16)b[2]; o[7] = (__bf16)b[3];
    return o;
}

// ---------------------------------------------------------------------------
// Kernel 1: fused QKV projection, operand-SWAPPED MFMA (A=W rows, B=x rows).
// (held control — near roofline per R7 back-solve)
// ---------------------------------------------------------------------------
__global__ __launch_bounds__(256) void proj_qkv(
    const float* __restrict__ xq, const float* __restrict__ xk, const float* __restrict__ xv,
    const float* __restrict__ Wq, const float* __restrict__ Wk, const float* __restrict__ Wv,
    const float* __restrict__ bq, const float* __restrict__ bk, const float* __restrict__ bv,
    __bf16* __restrict__ Qs, __bf16* __restrict__ Kb, __bf16* __restrict__ Vt)
{
    __shared__ __align__(16) char wlds[34816];        // 128 rows x 272 B
    const int z = blockIdx.z;
    const float* x    = (z == 0) ? xq : ((z == 1) ? xk : xv);
    const float* Wf   = (z == 0) ? Wq : ((z == 1) ? Wk : Wv);
    const float* bias = (z == 0) ? bq : ((z == 1) ? bk : bv);
    const int b    = blockIdx.y;
    const int tid  = threadIdx.x;
    const int wave = tid >> 6, lane = tid & 63;
    const int quad = lane >> 4, l15 = lane & 15;
    const int n0   = blockIdx.x * 64 + wave * 16;

    {   // stage W (fp32 -> bf16) into LDS: thread = half-row
        const int r = tid >> 1, half = tid & 1;
        const float* wsrc = Wf + r * DIM + half * 64;
        char* wdst = wlds + r * 272 + half * 128;
        #pragma unroll
        for (int i = 0; i < 8; i++)
            *(bf16x8*)(wdst + i * 16) = cvt8(wsrc + i * 8);
    }

    bf16x8 a[4];
    const float* xrow = x + (b * N_SEQ + n0 + l15) * DIM + quad * 8;
    a[0] = cvt8(xrow);      a[1] = cvt8(xrow + 32);
    a[2] = cvt8(xrow + 64); a[3] = cvt8(xrow + 96);
    __syncthreads();

    const int n = n0 + l15;                    // D col = n (swapped)
    for (int t = 0; t < 8; t++) {
        const char* wr = wlds + (t * 16 + l15) * 272 + quad * 16;
        bf16x8 w0 = *(const bf16x8*)(wr);
        bf16x8 w1 = *(const bf16x8*)(wr + 64);
        bf16x8 w2 = *(const bf16x8*)(wr + 128);
        bf16x8 w3 = *(const bf16x8*)(wr + 192);

        f32x4 acc = {0.f, 0.f, 0.f, 0.f};
        acc = MFMA(w0, a[0], acc);
        acc = MFMA(w1, a[1], acc);
        acc = MFMA(w2, a[2], acc);
        acc = MFMA(w3, a[3], acc);

        const int d0 = t * 16 + quad * 4;      // D row = d0 + r
        if (z == 0) {
            const int h = d0 >> 5, dh0 = d0 & 31;
            bf16x4 q4;
            #pragma unroll
            for (int r = 0; r < 4; r++)
                q4[r] = (__bf16)((acc[r] + bias[d0 + r]) * QSCALE);
            *(bf16x4*)(Qs + ((b * NH + h) * N_SEQ + n) * DH + dh0) = q4;
        } else if (z == 1) {
            const int h = d0 >> 5, dh0 = d0 & 31;
            bf16x4 k4;
            #pragma unroll
            for (int r = 0; r < 4; r++)
                k4[r] = (__bf16)(acc[r] + bias[d0 + r]);
            *(bf16x4*)(Kb + ((b * NH + h) * N_SEQ + n) * DH + dh0) = k4;
        } else {
            const int nl = n & 63;
            const int np = (n & ~63) | (nl & 35) | ((nl & 12) << 1) | ((nl & 16) >> 2);
            #pragma unroll
            for (int r = 0; r < 4; r++) {
                const int d = d0 + r, h = d >> 5, dh = d & 31;
                Vt[((b * NH + h) * DH + dh) * N_SEQ + np] = (__bf16)(acc[r] + bias[d]);
            }
        }
    }
}

// ---------------------------------------------------------------------------
// Kernel 2: attention — EXACT R2 body (best measured flash: 50.4-50.9 us).
// Session conclusions baked into this choice:
//  - 2 waves/SIMD + 64 q/wave + 128-key superblock is the balance point of
//    the {TRANS ~21us, MFMA ~16us, LDS ~40%} pipe triangle; every
//    perturbation regressed: 32q/4w (R1 63us, R5 53.7us — LDS saturates),
//    L2-direct (R3 58.9us — latency), launch_bounds(,4) (R4 — spill),
//    explicit phase reorder (R8 52.9us — compiler schedule was better).
//  - Verified wins kept: l-sum via ones-MFMA on the MFMA pipe, setprio
//    around MFMA clusters, both-tile fragment hoist, 1 barrier/superblock.
// ---------------------------------------------------------------------------
__global__ __launch_bounds__(256, 2) void flash_attn(
    const __bf16* __restrict__ Qs, const __bf16* __restrict__ Kb,
    const __bf16* __restrict__ Vt, __bf16* __restrict__ ctxb)
{
    // K: 2 kh x 2 buf x 2 tiles x 5120 = 40960
    // V: 2 kh x 2 buf x 2 tiles x 4608 = 36864
    __shared__ __align__(16) char smem[77824];
    char* const Kbase = smem;                  // + kh*20480 + cur*10240 + t*5120
    char* const Vbase = smem + 40960;          // + kh*18432 + cur*9216  + t*4608

    const int bid  = blockIdx.x;
    const int bh   = bid & 15;                 // consecutive blocks cycle heads
    const int qc   = bid >> 4;                 // 0..31, 128 queries each
    const int tid  = threadIdx.x;
    const int wave = tid >> 6, lane = tid & 63;
    const int quad = lane >> 4, l15 = lane & 15;
    const int qh   = wave & 1, kh = wave >> 1; // kh in {0,1}
    const int n0   = qc * 128 + qh * 64;
    const int KH   = 2048;                     // keys per kh

    // Q B-fragments: 4 tiles of 16 queries
    const __bf16* Qp = Qs + (bh * N_SEQ + n0) * DH;
    bf16x8 qf[4];
    #pragma unroll
    for (int q = 0; q < 4; q++)
        qf[q] = *(const bf16x8*)(Qp + (q * 16 + l15) * DH + quad * 8);

    // ones A-fragment for the l-sum MFMA (l = 1*P summed over frag keys)
    bf16x8 ones;
    #pragma unroll
    for (int i = 0; i < 8; i++) ones[i] = (__bf16)1.0f;

    // staging: thread covers one 16B chunk of each tile (4 K + 4 V per superblock)
    const int r_ = tid >> 2, c_ = tid & 3;
    const __bf16* gK = Kb + (size_t)bh * N_SEQ * DH + r_ * DH + c_ * 8;
    const __bf16* gV = Vt + ((size_t)bh * DH + (tid >> 3)) * N_SEQ + (tid & 7) * 8;
    const int kofsK = r_ * 80 + c_ * 16;
    const int kofsV = (tid >> 3) * 144 + (tid & 7) * 16;

    {   // prologue: superblock 0 (2 tiles) of both kh groups -> buf 0
        #pragma unroll
        for (int g = 0; g < 2; g++) {
            #pragma unroll
            for (int t = 0; t < 2; t++) {
                bf16x8 kr = *(const bf16x8*)(gK + (size_t)(g * KH + t * 64) * DH);
                bf16x8 vr = *(const bf16x8*)(gV + g * KH + t * 64);
                *(bf16x8*)(Kbase + g * 20480 + t * 5120 + kofsK) = kr;
                *(bf16x8*)(Vbase + g * 18432 + t * 4608 + kofsV) = vr;
            }
        }
    }
    __syncthreads();

    char* const Kme = Kbase + kh * 20480;
    char* const Vme = Vbase + kh * 18432;

    f32x4 c[4][2];
    f32x4 cl[4];
    const f32x4 z4 = {0.f,0.f,0.f,0.f};
    #pragma unroll
    for (int q = 0; q < 4; q++) { c[q][0] = z4; c[q][1] = z4; cl[q] = z4; }

    for (int kbb = 0; kbb < KH / 128; kbb++) { // 16 superblocks, 1 barrier each
        const int cur = kbb & 1;
        const char* Kc = Kme + cur * 10240;
        const char* Vc = Vme + cur * 9216;

        // prefetch next superblock for both kh groups (wraps; harmless)
        const int kn = (kbb + 1) & (KH / 128 - 1);
        bf16x8 krn[2][2], vrn[2][2];
        #pragma unroll
        for (int g = 0; g < 2; g++) {
            #pragma unroll
            for (int t = 0; t < 2; t++) {
                krn[g][t] = *(const bf16x8*)(gK + (size_t)(g * KH + kn * 128 + t * 64) * DH);
                vrn[g][t] = *(const bf16x8*)(gV + g * KH + kn * 128 + t * 64);
            }
        }

        // hoist ALL fragment ds_reads for BOTH 64-key tiles up front:
        // tile1's LDS latency hides under tile0's full compute chain.
        bf16x8 kfa[2][4], vfa[2][4];
        #pragma unroll
        for (int t = 0; t < 2; t++) {
            const char* Kt  = Kc + t * 5120;
            const char* Vtl = Vc + t * 4608;
            #pragma unroll
            for (int i = 0; i < 4; i++)
                kfa[t][i] = *(const bf16x8*)(Kt + (i * 16 + l15) * 80 + quad * 16);
            vfa[t][0] = *(const bf16x8*)(Vtl + l15 * 144 + quad * 16);
            vfa[t][1] = *(const bf16x8*)(Vtl + (16 + l15) * 144 + quad * 16);
            vfa[t][2] = *(const bf16x8*)(Vtl + l15 * 144 + 64 + quad * 16);
            vfa[t][3] = *(const bf16x8*)(Vtl + (16 + l15) * 144 + 64 + quad * 16);
        }

        #pragma unroll
        for (int t = 0; t < 2; t++) {          // two 64-key tiles, no barrier between
            // scores + P (in registers) per query tile
            bf16x8 pf[4][2];
            #pragma unroll
            for (int q = 0; q < 4; q++) {
                __builtin_amdgcn_s_setprio(1);
                f32x4 sa = MFMA(kfa[t][0], qf[q], z4);
                f32x4 sb = MFMA(kfa[t][1], qf[q], z4);
                f32x4 sc = MFMA(kfa[t][2], qf[q], z4);
                f32x4 sd = MFMA(kfa[t][3], qf[q], z4);
                __builtin_amdgcn_s_setprio(0);
                f32x4 ea = exp4(sa), eb = exp4(sb), ec = exp4(sc), ed = exp4(sd);
                pf[q][0] = pack8(ea, eb);      // keys g0
                pf[q][1] = pack8(ec, ed);      // keys g1
            }

            __builtin_amdgcn_s_setprio(1);
            #pragma unroll
            for (int q = 0; q < 4; q++) {
                c[q][0] = MFMA(vfa[t][0], pf[q][0], c[q][0]);
                c[q][1] = MFMA(vfa[t][1], pf[q][0], c[q][1]);
                c[q][0] = MFMA(vfa[t][2], pf[q][1], c[q][0]);
                c[q][1] = MFMA(vfa[t][3], pf[q][1], c[q][1]);
                cl[q]   = MFMA(ones, pf[q][0], cl[q]);   // l-sum on MFMA pipe
                cl[q]   = MFMA(ones, pf[q][1], cl[q]);
            }
            __builtin_amdgcn_s_setprio(0);
        }

        // stage next superblock into the other buffer
        #pragma unroll
        for (int g = 0; g < 2; g++) {
            #pragma unroll
            for (int t = 0; t < 2; t++) {
                *(bf16x8*)(Kbase + g * 20480 + (cur ^ 1) * 10240 + t * 5120 + kofsK) = krn[g][t];
                *(bf16x8*)(Vbase + g * 18432 + (cur ^ 1) * 9216 + t * 4608 + kofsV) = vrn[g][t];
            }
        }
        __syncthreads();
    }

    // split-K combine via the dead K LDS region
    if (kh == 1) {
        char* dst = smem + (qh * 64 + lane) * 144;
        #pragma unroll
        for (int q = 0; q < 4; q++) {
            *(f32x4*)(dst + (q * 2 + 0) * 16) = c[q][0];
            *(f32x4*)(dst + (q * 2 + 1) * 16) = c[q][1];
        }
        f32x4 lv = {cl[0][0], cl[1][0], cl[2][0], cl[3][0]};
        *(f32x4*)(dst + 128) = lv;
    }
    __syncthreads();
    if (kh == 0) {
        const char* src = smem + (qh * 64 + lane) * 144;
        f32x4 lp = *(const f32x4*)(src + 128);
        const int b = bh >> 2, h = bh & 3;
        #pragma unroll
        for (int q = 0; q < 4; q++) {
            c[q][0] += *(const f32x4*)(src + (q * 2 + 0) * 16);
            c[q][1] += *(const f32x4*)(src + (q * 2 + 1) * 16);
            const float inv = 1.0f / (cl[q][0] + lp[q]);
            const int qg = n0 + q * 16 + l15;
            __bf16* dst = ctxb + ((size_t)(b * N_SEQ + qg)) * DIM + h * DH + quad * 4;
            #pragma unroll
            for (int dt = 0; dt < 2; dt++) {
                f32x4 cc = c[q][dt];
                bf16x2 e0 = {(__bf16)(cc[0] * inv), (__bf16)(cc[1] * inv)};
                bf16x2 e1 = {(__bf16)(cc[2] * inv), (__bf16)(cc[3] * inv)};
                *(bf16x2*)(dst + dt * 16)     = e0;
                *(bf16x2*)(dst + dt * 16 + 2) = e1;
            }
        }
    }
}

// ---------------------------------------------------------------------------
// Kernel 3: output projection, operand-swapped + Wo staged in LDS.
// (held control — near roofline per R7 back-solve)
// ---------------------------------------------------------------------------
__global__ __launch_bounds__(256) void out_proj(
    const __bf16* __restrict__ ctxb, const float* __restrict__ Wo,
    const float* __restrict__ bo, float* __restrict__ out)
{
    __shared__ __align__(16) char wlds[34816];
    const int b    = blockIdx.y;
    const int tid  = threadIdx.x;
    const int wave = tid >> 6, lane = tid & 63;
    const int quad = lane >> 4, l15 = lane & 15;
    const int n0   = blockIdx.x * 64 + wave * 16;

    {   // stage Wo (fp32 -> bf16) into LDS
        const int r = tid >> 1, half = tid & 1;
        const float* wsrc = Wo + r * DIM + half * 64;
        char* wdst = wlds + r * 272 + half * 128;
        #pragma unroll
        for (int i = 0; i < 8; i++)
            *(bf16x8*)(wdst + i * 16) = cvt8(wsrc + i * 8);
    }

    bf16x8 a[4];
    const __bf16* crow = ctxb + (b * N_SEQ + n0 + l15) * DIM + quad * 8;
    a[0] = *(const bf16x8*)(crow);
    a[1] = *(const bf16x8*)(crow + 32);
    a[2] = *(const bf16x8*)(crow + 64);
    a[3] = *(const bf16x8*)(crow + 96);
    __syncthreads();

    const int n = n0 + l15;
    for (int t = 0; t < 8; t++) {
        const char* wr = wlds + (t * 16 + l15) * 272 + quad * 16;
        bf16x8 w0 = *(const bf16x8*)(wr);
        bf16x8 w1 = *(const bf16x8*)(wr + 64);
        bf16x8 w2 = *(const bf16x8*)(wr + 128);
        bf16x8 w3 = *(const bf16x8*)(wr + 192);

        f32x4 acc = {0.f, 0.f, 0.f, 0.f};
        acc = MFMA(w0, a[0], acc);
        acc = MFMA(w1, a[1], acc);
        acc = MFMA(w2, a[2], acc);
        acc = MFMA(w3, a[3], acc);

        const int d0 = t * 16 + quad * 4;
        float4 o;
        o.x = acc[0] + bo[d0];
        o.y = acc[1] + bo[d0 + 1];
        o.z = acc[2] + bo[d0 + 2];
        o.w = acc[3] + bo[d0 + 3];
        *(float4*)(out + (b * N_SEQ + n) * DIM + d0) = o;
    }
}

// ---------------------------------------------------------------------------
extern "C" void kernel_launch(void* const* d_in, const int* in_sizes, int n_in,
                              void* d_out, int out_size, void* d_ws, size_t ws_size,
                              hipStream_t stream)
{
    const float* query = (const float*)d_in[0];
    const float* key   = (const float*)d_in[1];
    const float* value = (const float*)d_in[2];
    const float* Wq = (const float*)d_in[3];
    const float* bq = (const float*)d_in[4];
    const float* Wk = (const float*)d_in[5];
    const float* bk = (const float*)d_in[6];
    const float* Wv = (const float*)d_in[7];
    const float* bv = (const float*)d_in[8];
    const float* Wo = (const float*)d_in[9];
    const float* bo = (const float*)d_in[10];
    float* out = (float*)d_out;

    char* ws = (char*)d_ws;
    const size_t e = (size_t)BATCH * N_SEQ * DIM;   // 2,097,152 elements
    __bf16* Qs   = (__bf16*)(ws);                   // 4 MB  [B,H,N,32] scaled
    __bf16* Kb   = (__bf16*)(ws + 2 * e);           // 4 MB  [B,H,N,32] identity
    __bf16* Vt   = (__bf16*)(ws + 4 * e);           // 4 MB  [B,H,32,N] key-permuted
    __bf16* ctxb = (__bf16*)(ws + 6 * e);           // 4 MB  [B,N,128]

    proj_qkv<<<dim3(64, BATCH, 3), 256, 0, stream>>>(
        query, key, value, Wq, Wk, Wv, bq, bk, bv, Qs, Kb, Vt);
    flash_attn<<<dim3(512), 256, 0, stream>>>(Qs, Kb, Vt, ctxb);
    out_proj<<<dim3(64, BATCH), 256, 0, stream>>>(ctxb, Wo, bo, out);
}